// Round 1
// baseline (20520.761 us; speedup 1.0000x reference)
//
#include <hip/hip_runtime.h>

// GRU decoder: B=16, S=2048, H=1024.
// Phase 1: xg = h_enc @ W_ih^T + b_ih  (MFMA bf16 GEMM, 32768x1024x3072)
// Phase 2: persistent-WG sequential scan, W_hh slices held in registers,
//          h broadcast via global bf16 buffer + device-scope barrier per step.

#define Bz 16
#define Sz 2048
#define Hz 1024
#define N3 3072
#define NWG 64          // scan workgroups (16 j-columns each)

typedef __bf16 bf16x8 __attribute__((ext_vector_type(8)));
typedef unsigned short ushort8 __attribute__((ext_vector_type(8)));
typedef float f32x4 __attribute__((ext_vector_type(4)));

__device__ __forceinline__ unsigned short f2bf(float f) {
    unsigned u = __float_as_uint(f);
    u += 0x7FFFu + ((u >> 16) & 1u);        // RNE
    return (unsigned short)(u >> 16);
}
__device__ __forceinline__ float bf2f(unsigned short s) {
    return __uint_as_float(((unsigned)s) << 16);
}
__device__ __forceinline__ ushort8 cvt8(float4 a, float4 b) {
    ushort8 v;
    v[0]=f2bf(a.x); v[1]=f2bf(a.y); v[2]=f2bf(a.z); v[3]=f2bf(a.w);
    v[4]=f2bf(b.x); v[5]=f2bf(b.y); v[6]=f2bf(b.z); v[7]=f2bf(b.w);
    return v;
}
__device__ __forceinline__ f32x4 mfma16(ushort8 a, ushort8 b, f32x4 c) {
    return __builtin_amdgcn_mfma_f32_16x16x32_bf16(
        __builtin_bit_cast(bf16x8, a), __builtin_bit_cast(bf16x8, b), c, 0, 0, 0);
}
__device__ __forceinline__ float sigm(float x) { return 1.0f / (1.0f + __expf(-x)); }

// ---------------- Phase 1: xg GEMM ----------------
// C[M=32768][N=3072] = A[h_enc] * W_ih^T, tiles 64x64, K-step 64.
__global__ __launch_bounds__(256) void xgemm(
        const float* __restrict__ A, const float* __restrict__ Wih,
        const float* __restrict__ b_ih, void* __restrict__ xg, int XF) {
    __shared__ unsigned short As[64 * 72];
    __shared__ unsigned short Bs[64 * 72];
    const int bid = blockIdx.x;
    const int n0 = (bid % 48) * 64;
    const int m0 = (bid / 48) * 64;
    const int tid = threadIdx.x;
    const int lane = tid & 63, w = tid >> 6;
    const int l16 = lane & 15, quad = lane >> 4;

    f32x4 acc[4] = {};
    for (int kb = 0; kb < Hz; kb += 64) {
        #pragma unroll
        for (int i = 0; i < 2; ++i) {
            int row = (tid >> 3) + i * 32;
            int kk = (tid & 7) * 8;
            const float4* ga = (const float4*)(A + (size_t)(m0 + row) * Hz + kb + kk);
            *(ushort8*)&As[row * 72 + kk] = cvt8(ga[0], ga[1]);
            const float4* gb = (const float4*)(Wih + (size_t)(n0 + row) * Hz + kb + kk);
            *(ushort8*)&Bs[row * 72 + kk] = cvt8(gb[0], gb[1]);
        }
        __syncthreads();
        const ushort8* arow = (const ushort8*)(As + (w * 16 + l16) * 72);
        ushort8 af0 = arow[quad], af1 = arow[4 + quad];
        #pragma unroll
        for (int ns = 0; ns < 4; ++ns) {
            const ushort8* brow = (const ushort8*)(Bs + (ns * 16 + l16) * 72);
            acc[ns] = mfma16(af0, brow[quad], acc[ns]);
            acc[ns] = mfma16(af1, brow[4 + quad], acc[ns]);
        }
        __syncthreads();
    }
    #pragma unroll
    for (int ns = 0; ns < 4; ++ns) {
        int col = n0 + ns * 16 + l16;
        float bi = b_ih[col];
        #pragma unroll
        for (int r = 0; r < 4; ++r) {
            size_t off = (size_t)(m0 + w * 16 + quad * 4 + r) * N3 + col;
            float v = acc[ns][r] + bi;
            if (XF) ((float*)xg)[off] = v;
            else    ((unsigned short*)xg)[off] = f2bf(v);
        }
    }
}

// ---------------- Phase 2: persistent scan ----------------
// 64 WGs x 256 threads. WG owns j in [jb, jb+16): W_hh rows {j, H+j, 2H+j}.
// Wave w handles K range [w*256, w*256+256) for all 3 gate groups (B-frags in regs).
__global__ __launch_bounds__(256, 1) void gru_scan(
        const float* __restrict__ Whh, const float* __restrict__ bhh,
        const void* __restrict__ xg, int XF,
        unsigned short* __restrict__ hbuf,   // 2 x [16][1024] bf16
        unsigned* __restrict__ bar,
        float* __restrict__ out) {
    __shared__ unsigned short h_s[16 * 1032];      // padded rows: 2-way bank alias only
    __shared__ float part[3 * 4 * 16 * 16];        // [g][w][m][n]
    const int tid = threadIdx.x;
    const int lane = tid & 63, w = tid >> 6;
    const int l16 = lane & 15, quad = lane >> 4;
    const int jb = blockIdx.x * 16;
    const int wK = w * 256;

    // Load W_hh B-fragments into registers (once).
    ushort8 wf[3][8];
    #pragma unroll
    for (int g = 0; g < 3; ++g) {
        const float* wrow = Whh + (size_t)(g * Hz + jb + l16) * Hz;
        #pragma unroll
        for (int kc = 0; kc < 8; ++kc) {
            const float4* p = (const float4*)(wrow + wK + kc * 32 + quad * 8);
            wf[g][kc] = cvt8(p[0], p[1]);
        }
    }

    // Per-thread gate identity: (b, j)
    const int b = tid >> 4, jl = tid & 15;
    const int j = jb + jl;
    const float bhr = bhh[j], bhz = bhh[Hz + j], bhn = bhh[2 * Hz + j];
    float hreg = 0.0f;

    unsigned tgt = 0;
    for (int t = 0; t < Sz; ++t) {
        // stage h_t (bf16) -> LDS
        const unsigned short* hb = hbuf + (size_t)(t & 1) * 16384;
        #pragma unroll
        for (int i = 0; i < 8; ++i) {
            int c = tid + i * 256;
            int bb = c >> 7, pos = (c & 127) * 8;
            *(uint4*)(h_s + bb * 1032 + pos) = *(const uint4*)(hb + bb * 1024 + pos);
        }
        __syncthreads();

        // MFMA: D[m=batch][n=row-in-group], K-split across waves
        f32x4 a3[3] = {};
        const ushort8* hrow = (const ushort8*)(h_s + l16 * 1032);
        const int kbase = (wK >> 3) + quad;
        #pragma unroll
        for (int kc = 0; kc < 8; ++kc) {
            ushort8 af = hrow[kbase + kc * 4];
            a3[0] = mfma16(af, wf[0][kc], a3[0]);
            a3[1] = mfma16(af, wf[1][kc], a3[1]);
            a3[2] = mfma16(af, wf[2][kc], a3[2]);
        }
        #pragma unroll
        for (int g = 0; g < 3; ++g)
            #pragma unroll
            for (int r = 0; r < 4; ++r)
                part[((g * 4 + w) * 16 + (quad * 4 + r)) * 16 + l16] = a3[g][r];
        __syncthreads();

        // gates for this thread's (b, j)
        float hr = 0, hz = 0, hn = 0;
        #pragma unroll
        for (int ww = 0; ww < 4; ++ww) {
            hr += part[((0 + ww) * 16 + b) * 16 + jl];
            hz += part[((4 + ww) * 16 + b) * 16 + jl];
            hn += part[((8 + ww) * 16 + b) * 16 + jl];
        }
        size_t xoff = (size_t)(b * Sz + t) * N3 + j;
        float xr, xz, xn;
        if (XF) {
            const float* xp = (const float*)xg;
            xr = xp[xoff]; xz = xp[xoff + Hz]; xn = xp[xoff + 2 * Hz];
        } else {
            const unsigned short* xp = (const unsigned short*)xg;
            xr = bf2f(xp[xoff]); xz = bf2f(xp[xoff + Hz]); xn = bf2f(xp[xoff + 2 * Hz]);
        }
        float r = sigm(xr + hr + bhr);
        float z = sigm(xz + hz + bhz);
        float n = tanhf(xn + r * (hn + bhn));
        float hnew = (1.0f - z) * n + z * hreg;
        hreg = hnew;
        out[(size_t)(b * Sz + t) * Hz + j] = hnew;
        hbuf[((t + 1) & 1) * 16384 + b * Hz + j] = f2bf(hnew);

        // device-scope barrier (monotone counter)
        __syncthreads();
        __builtin_amdgcn_fence(__ATOMIC_RELEASE, "agent");
        tgt += NWG;
        if (tid == 0) {
            __hip_atomic_fetch_add(bar, 1u, __ATOMIC_RELEASE, __HIP_MEMORY_SCOPE_AGENT);
            while (__hip_atomic_load(bar, __ATOMIC_ACQUIRE, __HIP_MEMORY_SCOPE_AGENT) < tgt)
                __builtin_amdgcn_s_sleep(1);
        }
        __syncthreads();
        __builtin_amdgcn_fence(__ATOMIC_ACQUIRE, "agent");
    }
}

extern "C" void kernel_launch(void* const* d_in, const int* in_sizes, int n_in,
                              void* d_out, int out_size, void* d_ws, size_t ws_size,
                              hipStream_t stream) {
    const float* h_enc = (const float*)d_in[0];
    const float* W_ih  = (const float*)d_in[1];
    const float* W_hh  = (const float*)d_in[2];
    const float* b_ih  = (const float*)d_in[3];
    const float* b_hh  = (const float*)d_in[4];
    float* out = (float*)d_out;

    const size_t M = (size_t)Bz * Sz;              // 32768
    const size_t XG32 = M * N3 * 4;                // 402,653,184
    const size_t XG16 = M * N3 * 2;                // 201,326,592
    const int XF = (ws_size >= XG32 + (1 << 17)) ? 1 : 0;
    const size_t xgb = XF ? XG32 : XG16;

    char* base = (char*)d_ws;
    void* xg = (void*)base;
    unsigned short* hbuf = (unsigned short*)(base + xgb);
    unsigned* bar = (unsigned*)(base + xgb + 65536);

    // zero h0 double-buffer + barrier counter (captured into the graph, runs every replay)
    hipMemsetAsync(base + xgb, 0, 65536 + 4096, stream);

    xgemm<<<dim3(512 * 48), dim3(256), 0, stream>>>(h_enc, W_ih, b_ih, xg, XF);
    gru_scan<<<dim3(NWG), dim3(256), 0, stream>>>(W_hh, b_hh, xg, XF, hbuf, bar, out);
}